// Round 1
// 366.105 us; speedup vs baseline: 1.0241x; 1.0241x over previous
//
#include <hip/hip_runtime.h>

constexpr int SEQ = 256;
constexpr int DIM = 1024;
constexpr float SCALE = 0.0625f;  // 1/sqrt(256)

typedef __attribute__((ext_vector_type(8))) short bf16x8;
typedef __attribute__((ext_vector_type(4))) float f32x4;
typedef unsigned short ushort_t;
typedef unsigned int uint_t;

__device__ __forceinline__ void gld_lds16(const void* g, void* l) {
  __builtin_amdgcn_global_load_lds(
      (const __attribute__((address_space(1))) unsigned int*)g,
      (__attribute__((address_space(3))) unsigned int*)l, 16, 0, 0);
}

__device__ __forceinline__ ushort_t f2bf(float f) {  // round-to-nearest-even
  uint_t u = __float_as_uint(f);
  return (ushort_t)((u + 0x7fffu + ((u >> 16) & 1u)) >> 16);
}

// ---------------- prep_a: A_bf[m][k] = bf16(x + pos), row-major [16384][1024] ----------
__global__ __launch_bounds__(256)
void prep_a(const float* __restrict__ x, const float* __restrict__ pos,
            ushort_t* __restrict__ Ab) {
  const size_t idx = ((size_t)blockIdx.x * 256 + threadIdx.x) * 8;
  const int m = (int)(idx >> 10), k = (int)(idx & 1023);
  float4 x0 = *(const float4*)(x + idx);
  float4 x1 = *(const float4*)(x + idx + 4);
  const float* pp = pos + ((size_t)(m & 255) << 10) + k;
  float4 p0 = *(const float4*)pp;
  float4 p1 = *(const float4*)(pp + 4);
  uint_t w0 = (uint_t)f2bf(x0.x + p0.x) | ((uint_t)f2bf(x0.y + p0.y) << 16);
  uint_t w1 = (uint_t)f2bf(x0.z + p0.z) | ((uint_t)f2bf(x0.w + p0.w) << 16);
  uint_t w2 = (uint_t)f2bf(x1.x + p1.x) | ((uint_t)f2bf(x1.y + p1.y) << 16);
  uint_t w3 = (uint_t)f2bf(x1.z + p1.z) | ((uint_t)f2bf(x1.w + p1.w) << 16);
  *(uint4*)&Ab[idx] = make_uint4(w0, w1, w2, w3);
}

// ---------------- pack_w: W[k][n] fp32 -> bf16 tiles [nb 12][kc 16][n 256][k 64] -------
__global__ __launch_bounds__(256)
void pack_w(const float* __restrict__ Wq, const float* __restrict__ Wk,
            const float* __restrict__ Wv, ushort_t* __restrict__ Bp) {
  const float* W = (blockIdx.z == 0) ? Wq : (blockIdx.z == 1) ? Wk : Wv;
  const int n  = blockIdx.x * 256 + threadIdx.x;
  const int k8 = blockIdx.y * 8;
  uint_t h[8];
#pragma unroll
  for (int i = 0; i < 8; ++i) h[i] = f2bf(W[(size_t)(k8 + i) * DIM + n]);
  uint_t hp[4];
#pragma unroll
  for (int j = 0; j < 4; ++j) hp[j] = h[2 * j] | (h[2 * j + 1] << 16);
  const int np = blockIdx.z * 1024 + n;
  const int nb = np >> 8, nl = np & 255;
  const int kc = k8 >> 6, kk = k8 & 63;
  size_t base = (((size_t)nb * 16 + kc) * 256 + nl) * 64 + kk;
  *(uint4*)&Bp[base] = make_uint4(hp[0], hp[1], hp[2], hp[3]);
}

// ---------------- qkv: 256x256 tile, BK=64, 8 waves, 8-phase counted-vmcnt schedule ----
// Per-wave output 128x64 (2x4 wave grid), acc[8][4]. LDS 128 KiB (2 bufs of A 32K + B 32K).
// Staging quantum = quarter tile (64 rows x 64 k = 8 KiB = 1 gld_lds/thread, 1/phase).
// Steady state per K-tile t: p0 stage Bq2,Bq3(t+1); p1 stage Aq1,Aq3(t+1) [vmcnt(8)];
// p2 stage Bq0,Bq1(t+2)->buf[cur]; p3 stage Aq0,Aq2(t+2)->buf[cur] [vmcnt(6)].
// vmcnt(6) at tile end leaves 3 stage-pairs in flight across the boundary (never drains).
// XOR-swizzle applied on global SOURCE side; LDS dest lane-linear; reads use same XOR.
__global__ __launch_bounds__(512, 2)
void qkv_mfma(const ushort_t* __restrict__ Ab, const ushort_t* __restrict__ Bp,
              ushort_t* __restrict__ q_bf, ushort_t* __restrict__ k_bf,
              ushort_t* __restrict__ vT_bf) {
  const int nb = blockIdx.x;   // 0..11
  const int mb = blockIdx.y;   // 0..63 (one batch row-block each)
  const int tid = (int)threadIdx.x;
  const int wave = tid >> 6, lane = tid & 63;
  const int wm = wave >> 2, wn = wave & 3;
  const int l15 = lane & 15, quad = lane >> 4;

  __shared__ ushort_t smem[65536];  // buf c: A @ c*32768, B @ c*32768+16384 (ushorts)

  // staging constants: thread -> row band r8, phys chunk lane&7, fetch logical chunk ^r8
  const int r8 = lane >> 3;
  const int lc8 = ((lane & 7) ^ r8) * 8;
  const size_t a_row = ((size_t)(mb * 256 + wave * 8 + r8)) << 10;
  const size_t b_row = ((size_t)((nb * 16) * 256 + wave * 8 + r8)) << 6;
  const int wb = wave * 512;

#define SA(q, tt, c) gld_lds16(Ab + a_row + ((size_t)(q) << 16) + (size_t)(tt) * 64 + lc8, \
                               smem + (c) * 32768 + (q) * 4096 + wb)
#define SB(q, tt, c) gld_lds16(Bp + b_row + (size_t)(tt) * 16384 + (q) * 4096 + lc8, \
                               smem + (c) * 32768 + 16384 + (q) * 4096 + wb)

  // fragment read offsets (ushort idx): row*64 + ((ks*4+quad)^(row&7))*8
  const int swz = l15 & 7;
  const int cko0 = (quad ^ swz) * 8;
  const int cko1 = ((4 + quad) ^ swz) * 8;
  const int arow0 = (wm * 128 + l15) * 64;
  const int brow0 = (wn * 64 + l15) * 64;

  f32x4 acc[8][4] = {};
  bf16x8 a_cur[4][2], b_all[4][2];

#define LDA(IH) do { _Pragma("unroll") for (int ii = 0; ii < 4; ++ii) { \
    const int ro = arow0 + ((IH) * 64 + ii * 16) * 64; \
    a_cur[ii][0] = *(const bf16x8*)&Ac[ro + cko0]; \
    a_cur[ii][1] = *(const bf16x8*)&Ac[ro + cko1]; } } while (0)
#define LDB(J) do { const int ro = brow0 + (J) * 1024; \
    b_all[J][0] = *(const bf16x8*)&Bc[ro + cko0]; \
    b_all[J][1] = *(const bf16x8*)&Bc[ro + cko1]; } while (0)
#define MM(IH, J0) do { \
    asm volatile("s_waitcnt lgkmcnt(0)" ::: "memory"); \
    __builtin_amdgcn_s_setprio(1); \
    _Pragma("unroll") for (int ks = 0; ks < 2; ++ks) \
    _Pragma("unroll") for (int ii = 0; ii < 4; ++ii) \
    _Pragma("unroll") for (int jj = 0; jj < 2; ++jj) \
      acc[(IH)*4+ii][(J0)+jj] = __builtin_amdgcn_mfma_f32_16x16x32_bf16( \
          a_cur[ii][ks], b_all[(J0)+jj][ks], acc[(IH)*4+ii][(J0)+jj], 0, 0, 0); \
    __builtin_amdgcn_s_setprio(0); } while (0)

  // prologue: tile0 complete (deadline-ordered) + tile1 {Bq0,Bq1,Aq0,Aq2}
  SA(0, 0, 0); SA(2, 0, 0); SB(0, 0, 0); SB(1, 0, 0); SB(2, 0, 0); SB(3, 0, 0);
  SA(1, 0, 0); SA(3, 0, 0);
  SB(0, 1, 1); SB(1, 1, 1); SA(0, 1, 1); SA(2, 1, 1);
  asm volatile("s_waitcnt vmcnt(6)" ::: "memory");
  __builtin_amdgcn_s_barrier();

  for (int t = 0; t < 16; ++t) {
    const int cur = t & 1, nxt = cur ^ 1;
    const int tn  = (t < 15) ? t + 1 : 15;   // clamped re-stage is idempotent (same bytes)
    const int tn2 = (t < 14) ? t + 2 : 15;
    const ushort_t* Ac = &smem[cur * 32768];
    const ushort_t* Bc = Ac + 16384;
    // p0: read A-rh0 + B-cf01 | stage Bq2,Bq3(t+1)
    LDA(0); LDB(0); LDB(1);
    SB(2, tn, nxt); SB(3, tn, nxt);
    __builtin_amdgcn_s_barrier();
    MM(0, 0);
    __builtin_amdgcn_s_barrier();
    // p1: read B-cf23 | stage Aq1,Aq3(t+1) | vmcnt(8) makes Aq1,Aq3(t) safe for p2
    LDB(2); LDB(3);
    SA(1, tn, nxt); SA(3, tn, nxt);
    __builtin_amdgcn_s_barrier();
    MM(0, 2);
    asm volatile("s_waitcnt vmcnt(8)" ::: "memory");
    __builtin_amdgcn_s_barrier();
    // p2: read A-rh1 | stage Bq0,Bq1(t+2) into buf[cur] (B(t) fully consumed at p1)
    LDA(1);
    SB(0, tn2, cur); SB(1, tn2, cur);
    __builtin_amdgcn_s_barrier();
    MM(1, 2);
    __builtin_amdgcn_s_barrier();
    // p3: no reads | stage Aq0,Aq2(t+2) | vmcnt(6): D0(t+1) landed, 3 pairs in flight
    SA(0, tn2, cur); SA(2, tn2, cur);
    __builtin_amdgcn_s_barrier();
    MM(1, 0);
    asm volatile("s_waitcnt vmcnt(6)" ::: "memory");
    __builtin_amdgcn_s_barrier();
  }

  // epilogue: drain our async LDS writes before reuse/exit
  asm volatile("s_waitcnt vmcnt(0)" ::: "memory");
  const int wq = nb >> 2;                 // 0=q,1=k,2=v (block-uniform)
  const int h  = (nb & 3) * 4 + wn;       // head (wave-uniform)
  if (wq < 2) {
    ushort_t* base = ((wq == 0) ? q_bf : k_bf) + (size_t)(mb * 16 + h) * (SEQ * 64);
    const int tb = wm * 128 + quad * 4;
#pragma unroll
    for (int i = 0; i < 8; ++i)
#pragma unroll
      for (int j = 0; j < 4; ++j) {
        const int d = j * 16 + l15;
#pragma unroll
        for (int r = 0; r < 4; ++r)
          base[(size_t)(tb + i * 16 + r) * 64 + d] = f2bf(acc[i][j][r]);
      }
  } else {
    __builtin_amdgcn_s_barrier();  // all waves drained -> safe to overwrite smem
    ushort_t* L = &smem[wave * 4608];   // 64x72-pad transpose tile per wave
    ushort_t* vbase = vT_bf + (size_t)(mb * 16 + h) * (64 * SEQ) + wm * 128;
    const int tc = (lane & 7) * 8;
#pragma unroll
    for (int g = 0; g < 2; ++g) {
#pragma unroll
      for (int ii = 0; ii < 4; ++ii)
#pragma unroll
        for (int j = 0; j < 4; ++j) {
          f32x4 v = acc[g * 4 + ii][j];
          uint_t lo = (uint_t)f2bf(v[0]) | ((uint_t)f2bf(v[1]) << 16);
          uint_t hi = (uint_t)f2bf(v[2]) | ((uint_t)f2bf(v[3]) << 16);
          *(uint2*)&L[(j * 16 + l15) * 72 + ii * 16 + quad * 4] = make_uint2(lo, hi);
        }
#pragma unroll
      for (int u = 0; u < 8; ++u) {
        const int d = u * 8 + r8;
        uint4 val = *(const uint4*)&L[d * 72 + tc];
        *(uint4*)&vbase[(size_t)d * SEQ + g * 64 + tc] = val;
      }
    }
  }
#undef SA
#undef SB
#undef LDA
#undef LDB
#undef MM
}

// ---------------- stats: partial l[t,s] = sum_{b'} e over 4 b' per wave-slot ----------------
__global__ __launch_bounds__(256)
void stats_mfma(const ushort_t* __restrict__ qb, const ushort_t* __restrict__ kb,
                float* __restrict__ part_l) {
  const int p = blockIdx.x, g = blockIdx.y;
  int tt, ss;
  if (p < 4) { tt = p; ss = p; }
  else {
    const int idx = p - 4;
    tt = (idx < 3) ? 0 : (idx < 5) ? 1 : 2;
    ss = (idx < 3) ? idx + 1 : (idx < 5) ? idx - 1 : 3;
  }
  const bool diag = (p < 4);
  const int tid = threadIdx.x, wave = tid >> 6, lane = tid & 63;
  const int l15 = lane & 15, quad = lane >> 4;
  const int slot = g * 4 + wave;

  f32x4 lacc[4][4] = {};

  for (int i4 = 0; i4 < 4; ++i4) {
    const int bp = slot * 4 + i4;
    const int bh = (bp & 63) * 16 + (bp >> 6);
    const ushort_t* qt = qb + (size_t)bh * (SEQ * 64) + (size_t)(tt * 64) * 64;
    const ushort_t* kt = kb + (size_t)bh * (SEQ * 64) + (size_t)(ss * 64) * 64;
    bf16x8 aq[4][2], bk[4][2];
#pragma unroll
    for (int m = 0; m < 4; ++m)
#pragma unroll
      for (int ks = 0; ks < 2; ++ks) {
        aq[m][ks] = *(const bf16x8*)&qt[(m * 16 + l15) * 64 + ks * 32 + quad * 8];
        bk[m][ks] = *(const bf16x8*)&kt[(m * 16 + l15) * 64 + ks * 32 + quad * 8];
      }
    f32x4 sf[4][4] = {};
#pragma unroll
    for (int ks = 0; ks < 2; ++ks)
#pragma unroll
      for (int m = 0; m < 4; ++m)
#pragma unroll
        for (int n = 0; n < 4; ++n)
          sf[m][n] = __builtin_amdgcn_mfma_f32_16x16x32_bf16(aq[m][ks], bk[n][ks], sf[m][n], 0, 0, 0);
#pragma unroll
    for (int m = 0; m < 4; ++m)
#pragma unroll
      for (int n = 0; n < 4; ++n)
#pragma unroll
        for (int r = 0; r < 4; ++r) {
          float e = __expf(sf[m][n][r] * SCALE);
          if (diag) {
            const int t = tt * 64 + m * 16 + quad * 4 + r;
            const int s = ss * 64 + n * 16 + l15;
            e = (s > t) ? e : 1.0f;
          }
          lacc[m][n][r] += e;
        }
  }
  float* pl = part_l + (size_t)slot * (SEQ * SEQ);
#pragma unroll
  for (int m = 0; m < 4; ++m)
#pragma unroll
    for (int r = 0; r < 4; ++r) {
      const int t = tt * 64 + m * 16 + quad * 4 + r;
#pragma unroll
      for (int n = 0; n < 4; ++n)
        pl[(size_t)t * SEQ + ss * 64 + n * 16 + l15] = lacc[m][n][r];
    }
}

// ---------------- merge: sum 256 slots -> inv_lT[s][t]; 8 accumulators for MLP ----------------
__global__ __launch_bounds__(256)
void merge_kernel(const float* __restrict__ part_l, float* __restrict__ inv_lT) {
  const int i = blockIdx.x * 256 + threadIdx.x;  // t*256+s
  const int t = i >> 8, s = i & 255;
  float invv;
  if (s <= t) invv = 1.0f / 1024.0f;
  else {
    const float* p = part_l + i;
    float a0 = 0.f, a1 = 0.f, a2 = 0.f, a3 = 0.f,
          a4 = 0.f, a5 = 0.f, a6 = 0.f, a7 = 0.f;
    for (int g = 0; g < 256; g += 8) {
      const float* q = p + ((size_t)g << 16);
      a0 += q[0ull << 16]; a1 += q[1ull << 16]; a2 += q[2ull << 16]; a3 += q[3ull << 16];
      a4 += q[4ull << 16]; a5 += q[5ull << 16]; a6 += q[6ull << 16]; a7 += q[7ull << 16];
    }
    invv = 1.0f / (((a0 + a1) + (a2 + a3)) + ((a4 + a5) + (a6 + a7)));
  }
  inv_lT[s * SEQ + t] = invv;
}

// ---------------- pv: recompute S^T, P=e*inv (bf16, LDS), O = P.V via MFMA ----------------
__global__ __launch_bounds__(256)
void pv_mfma(const ushort_t* __restrict__ qb, const ushort_t* __restrict__ kb,
             const ushort_t* __restrict__ vtb, const float* __restrict__ inv_lT,
             float* __restrict__ out) {
  const int bh = blockIdx.x;
  const int b = bh >> 4, h = bh & 15;
  const int tid = threadIdx.x, wave = tid >> 6, lane = tid & 63;
  const int l15 = lane & 15, quad = lane >> 4;
  const int t0 = wave * 64;

  __shared__ ushort_t Plds[4][64][72];
  ushort_t (*Pw)[72] = Plds[wave];

  const ushort_t* qq = qb + (size_t)bh * (SEQ * 64);
  const ushort_t* kk = kb + (size_t)bh * (SEQ * 64);
  const ushort_t* vv = vtb + (size_t)bh * (64 * SEQ);

  bf16x8 qf[4][2];
#pragma unroll
  for (int nt = 0; nt < 4; ++nt)
#pragma unroll
    for (int ks = 0; ks < 2; ++ks)
      qf[nt][ks] = *(const bf16x8*)&qq[(t0 + nt * 16 + l15) * 64 + ks * 32 + quad * 8];

  f32x4 o[4][4] = {};

  for (int sc = 0; sc < 4; ++sc) {
    if (sc < wave) {
      const uint_t c = 0x3A803A80u;  // bf16 1/1024, exact
      const uint4 cc = make_uint4(c, c, c, c);
#pragma unroll
      for (int u = 0; u < 8; ++u) *(uint4*)&Pw[lane][u * 8] = cc;
    } else {
      bf16x8 kf[4][2];
#pragma unroll
      for (int ms = 0; ms < 4; ++ms)
#pragma unroll
        for (int ks = 0; ks < 2; ++ks)
          kf[ms][ks] = *(const bf16x8*)&kk[(sc * 64 + ms * 16 + l15) * 64 + ks * 32 + quad * 8];
      f32x4 sf[4][4] = {};
#pragma unroll
      for (int ks = 0; ks < 2; ++ks)
#pragma unroll
        for (int ms = 0; ms < 4; ++ms)
#pragma unroll
          for (int nt = 0; nt < 4; ++nt)
            sf[ms][nt] = __builtin_amdgcn_mfma_f32_16x16x32_bf16(kf[ms][ks], qf[nt][ks], sf[ms][nt], 0, 0, 0);
      const bool dg = (sc == wave);
      const int t = t0 + l15;
#pragma unroll
      for (int ms = 0; ms < 4; ++ms)
#pragma unroll
        for (int nt = 0; nt < 4; ++nt) {
          const int sb = sc * 64 + ms * 16 + quad * 4;
          const int tc = t + nt * 16;
          ushort_t pb[4];
#pragma unroll
          for (int r = 0; r < 4; ++r) {
            const int s = sb + r;
            float e = __expf(sf[ms][nt][r] * SCALE);
            if (dg) e = (s > tc) ? e : 1.0f;
            pb[r] = f2bf(e * inv_lT[(size_t)s * SEQ + tc]);
          }
          uint_t lo = (uint_t)pb[0] | ((uint_t)pb[1] << 16);
          uint_t hi = (uint_t)pb[2] | ((uint_t)pb[3] << 16);
          *(uint2*)&Pw[nt * 16 + l15][ms * 16 + quad * 4] = make_uint2(lo, hi);
        }
    }
    bf16x8 vf[4][2], pf[4][2];
#pragma unroll
    for (int nd = 0; nd < 4; ++nd)
#pragma unroll
      for (int ks = 0; ks < 2; ++ks)
        vf[nd][ks] = *(const bf16x8*)&vv[(nd * 16 + l15) * SEQ + sc * 64 + ks * 32 + quad * 8];
#pragma unroll
    for (int mt = 0; mt < 4; ++mt)
#pragma unroll
      for (int ks = 0; ks < 2; ++ks)
        pf[mt][ks] = *(const bf16x8*)&Pw[mt * 16 + l15][ks * 32 + quad * 8];
#pragma unroll
    for (int ks = 0; ks < 2; ++ks)
#pragma unroll
      for (int mt = 0; mt < 4; ++mt)
#pragma unroll
        for (int nd = 0; nd < 4; ++nd)
          o[mt][nd] = __builtin_amdgcn_mfma_f32_16x16x32_bf16(pf[mt][ks], vf[nd][ks], o[mt][nd], 0, 0, 0);
  }

  float* ob = out + (size_t)b * SEQ * DIM + h * 64;
#pragma unroll
  for (int mt = 0; mt < 4; ++mt)
#pragma unroll
    for (int r = 0; r < 4; ++r) {
      const int t = t0 + mt * 16 + quad * 4 + r;
#pragma unroll
      for (int nd = 0; nd < 4; ++nd)
        ob[(size_t)t * DIM + nd * 16 + l15] = o[mt][nd][r];
    }
}

extern "C" void kernel_launch(void* const* d_in, const int* in_sizes, int n_in,
                              void* d_out, int out_size, void* d_ws, size_t ws_size,
                              hipStream_t stream) {
  const float* x   = (const float*)d_in[0];
  const float* pos = (const float*)d_in[1];
  const float* Wq  = (const float*)d_in[2];
  const float* Wk  = (const float*)d_in[3];
  const float* Wv  = (const float*)d_in[4];
  float* out = (float*)d_out;

  // A_bf (33.5 MB) + Bp (6.3 MB) live in d_out (67 MB); both are dead before
  // pv_mfma fully overwrites d_out.
  ushort_t* Ab = (ushort_t*)d_out;
  ushort_t* Bp = (ushort_t*)((char*)d_out + 33554432);

  char* W = (char*)d_ws;  // 168.0 MB total
  ushort_t* q_bf   = (ushort_t*)(W);                  //  33,554,432 B  [b][h][t][d]
  ushort_t* k_bf   = (ushort_t*)(W + 33554432);       //  33,554,432 B
  ushort_t* vT_bf  = (ushort_t*)(W + 67108864);       //  33,554,432 B  [b][h][d][t]
  float*    part_l = (float*)  (W + 100663296);       //  67,108,864 B  (256 slots)
  float*    inv_lT = (float*)  (W + 167772160);       //     262,144 B

  prep_a<<<dim3(8192), 256, 0, stream>>>(x, pos, Ab);
  pack_w<<<dim3(4, 128, 3), 256, 0, stream>>>(Wq, Wk, Wv, Bp);
  qkv_mfma<<<dim3(12, 64), 512, 0, stream>>>(Ab, Bp, q_bf, k_bf, vT_bf);
  stats_mfma<<<dim3(10, 64), 256, 0, stream>>>(q_bf, k_bf, part_l);
  merge_kernel<<<dim3(SEQ * SEQ / 256), 256, 0, stream>>>(part_l, inv_lT);
  pv_mfma<<<dim3(1024), 256, 0, stream>>>(q_bf, k_bf, vT_bf, inv_lT, out);
}

// Round 2
// 350.661 us; speedup vs baseline: 1.0692x; 1.0440x over previous
//
#include <hip/hip_runtime.h>

constexpr int SEQ = 256;
constexpr int DIM = 1024;
constexpr float SCALE = 0.0625f;  // 1/sqrt(256)

typedef __attribute__((ext_vector_type(8))) short bf16x8;
typedef __attribute__((ext_vector_type(4))) float f32x4;
typedef unsigned short ushort_t;
typedef unsigned int uint_t;

__device__ __forceinline__ void gld_lds16(const void* g, void* l) {
  __builtin_amdgcn_global_load_lds(
      (const __attribute__((address_space(1))) unsigned int*)g,
      (__attribute__((address_space(3))) unsigned int*)l, 16, 0, 0);
}

__device__ __forceinline__ ushort_t f2bf(float f) {  // round-to-nearest-even
  uint_t u = __float_as_uint(f);
  return (ushort_t)((u + 0x7fffu + ((u >> 16) & 1u)) >> 16);
}

// ---------------- prep_a: A_bf[m][k] = bf16(x + pos), row-major [16384][1024] ----------
__global__ __launch_bounds__(256)
void prep_a(const float* __restrict__ x, const float* __restrict__ pos,
            ushort_t* __restrict__ Ab) {
  const size_t idx = ((size_t)blockIdx.x * 256 + threadIdx.x) * 8;
  const int m = (int)(idx >> 10), k = (int)(idx & 1023);
  float4 x0 = *(const float4*)(x + idx);
  float4 x1 = *(const float4*)(x + idx + 4);
  const float* pp = pos + ((size_t)(m & 255) << 10) + k;
  float4 p0 = *(const float4*)pp;
  float4 p1 = *(const float4*)(pp + 4);
  uint_t w0 = (uint_t)f2bf(x0.x + p0.x) | ((uint_t)f2bf(x0.y + p0.y) << 16);
  uint_t w1 = (uint_t)f2bf(x0.z + p0.z) | ((uint_t)f2bf(x0.w + p0.w) << 16);
  uint_t w2 = (uint_t)f2bf(x1.x + p1.x) | ((uint_t)f2bf(x1.y + p1.y) << 16);
  uint_t w3 = (uint_t)f2bf(x1.z + p1.z) | ((uint_t)f2bf(x1.w + p1.w) << 16);
  *(uint4*)&Ab[idx] = make_uint4(w0, w1, w2, w3);
}

// ---------------- pack_w: W[k][n] fp32 -> bf16 tiles [nb 12][kc 16][n 256][k 64] -------
__global__ __launch_bounds__(256)
void pack_w(const float* __restrict__ Wq, const float* __restrict__ Wk,
            const float* __restrict__ Wv, ushort_t* __restrict__ Bp) {
  const float* W = (blockIdx.z == 0) ? Wq : (blockIdx.z == 1) ? Wk : Wv;
  const int n  = blockIdx.x * 256 + threadIdx.x;
  const int k8 = blockIdx.y * 8;
  uint_t h[8];
#pragma unroll
  for (int i = 0; i < 8; ++i) h[i] = f2bf(W[(size_t)(k8 + i) * DIM + n]);
  uint_t hp[4];
#pragma unroll
  for (int j = 0; j < 4; ++j) hp[j] = h[2 * j] | (h[2 * j + 1] << 16);
  const int np = blockIdx.z * 1024 + n;
  const int nb = np >> 8, nl = np & 255;
  const int kc = k8 >> 6, kk = k8 & 63;
  size_t base = (((size_t)nb * 16 + kc) * 256 + nl) * 64 + kk;
  *(uint4*)&Bp[base] = make_uint4(hp[0], hp[1], hp[2], hp[3]);
}

// ---------------- qkv: 256x256 tile, BK=64, 8 waves, counted lgkm/vmcnt pipeline ------
// Tile schedule (5 barriers): reads that feed burst N+1 are issued before burst N and
// retire under it (counted lgkmcnt). a1 reload is split in halves interleaved inside
// M02 so af[] is single-buffered (no extra VGPR). Staging invariants:
//   entry: buf[cur] fully landed except Aq1,Aq3 (in flight as the 2 oldest vm ops);
//   vmcnt(8) after M00 completes exactly those two; vmcnt(6) at tile end restores
//   the 6-in-flight invariant {SA1,SA3(t+1), SB0,SB1(t+2), SA0,SA2(t+2)}.
// Reads of buf[cur] always complete (per-wave lgkm + barrier) before any SB/SA-into-cur
// write issues, which also keeps the clamped tail re-stages benign.
__global__ __launch_bounds__(512, 2)
void qkv_mfma(const ushort_t* __restrict__ Ab, const ushort_t* __restrict__ Bp,
              ushort_t* __restrict__ q_bf, ushort_t* __restrict__ k_bf,
              ushort_t* __restrict__ vT_bf) {
  const int nb = blockIdx.x;   // 0..11
  const int mb = blockIdx.y;   // 0..63
  const int tid = (int)threadIdx.x;
  const int wave = tid >> 6, lane = tid & 63;
  const int wm = wave >> 2, wn = wave & 3;
  const int l15 = lane & 15, quad = lane >> 4;

  __shared__ ushort_t smem[65536];  // buf c: A @ c*32768, B @ c*32768+16384 (ushorts)

  // staging constants: thread -> row band r8, phys chunk lane&7, fetch logical chunk ^r8
  const int r8 = lane >> 3;
  const int lc8 = ((lane & 7) ^ r8) * 8;
  const size_t a_row = ((size_t)(mb * 256 + wave * 8 + r8)) << 10;
  const size_t b_row = ((size_t)((nb * 16) * 256 + wave * 8 + r8)) << 6;
  const int wb = wave * 512;

#define SA(q, tt, c) gld_lds16(Ab + a_row + ((size_t)(q) << 16) + (size_t)(tt) * 64 + lc8, \
                               smem + (c) * 32768 + (q) * 4096 + wb)
#define SB(q, tt, c) gld_lds16(Bp + b_row + (size_t)(tt) * 16384 + (q) * 4096 + lc8, \
                               smem + (c) * 32768 + 16384 + (q) * 4096 + wb)

  // fragment read offsets (ushort idx): row*64 + ((ks*4+quad)^(row&7))*8
  const int swz = l15 & 7;
  const int cko0 = (quad ^ swz) * 8;
  const int cko1 = ((4 + quad) ^ swz) * 8;
  const int arow0 = (wm * 128 + l15) * 64;
  const int brow0 = (wn * 64 + l15) * 64;

  f32x4 acc[8][4] = {};
  bf16x8 af[4][2], bf[4][2];

#define LDA_II(IH, ii) do { \
    const int ro = arow0 + ((IH) * 64 + (ii) * 16) * 64; \
    af[ii][0] = *(const bf16x8*)&Ac[ro + cko0]; \
    af[ii][1] = *(const bf16x8*)&Ac[ro + cko1]; } while (0)
#define LDB_J(J) do { const int ro = brow0 + (J) * 1024; \
    bf[J][0] = *(const bf16x8*)&Bc[ro + cko0]; \
    bf[J][1] = *(const bf16x8*)&Bc[ro + cko1]; } while (0)
#define MMQ(IH, II0, II1, J0) do { \
    _Pragma("unroll") for (int ks = 0; ks < 2; ++ks) \
    _Pragma("unroll") for (int ii = (II0); ii < (II1); ++ii) \
    _Pragma("unroll") for (int jj = 0; jj < 2; ++jj) \
      acc[(IH) * 4 + ii][(J0) + jj] = __builtin_amdgcn_mfma_f32_16x16x32_bf16( \
          af[ii][ks], bf[(J0) + jj][ks], acc[(IH) * 4 + ii][(J0) + jj], 0, 0, 0); \
    } while (0)

  // prologue: tile0 complete + tile1 {Bq0,Bq1,Aq0,Aq2}; vmcnt(6) leaves the invariant set
  SA(0, 0, 0); SA(2, 0, 0); SB(0, 0, 0); SB(1, 0, 0); SB(2, 0, 0); SB(3, 0, 0);
  SA(1, 0, 0); SA(3, 0, 0);
  SB(0, 1, 1); SB(1, 1, 1); SA(0, 1, 1); SA(2, 1, 1);
  asm volatile("s_waitcnt vmcnt(6)" ::: "memory");
  __builtin_amdgcn_s_barrier();

  for (int t = 0; t < 16; ++t) {
    const int cur = t & 1, nxt = cur ^ 1;
    const int tn  = (t < 15) ? t + 1 : 15;   // clamped re-stage is benign (reads done first)
    const int tn2 = (t < 14) ? t + 2 : 15;
    const ushort_t* Ac = &smem[cur * 32768];
    const ushort_t* Bc = Ac + 16384;
    // P0: issue a0 (8r) + b01 (4r) | stage Bq2,Bq3(t+1)
    LDA_II(0, 0); LDA_II(0, 1); LDA_II(0, 2); LDA_II(0, 3);
    LDB_J(0); LDB_J(1);
    SB(2, tn, nxt); SB(3, tn, nxt);
    __builtin_amdgcn_s_barrier();
    // P1: issue b23 ahead (flies under M00) | stage Aq1,Aq3(t+1) | M00 | vmcnt(8)
    LDB_J(2); LDB_J(3);
    SA(1, tn, nxt); SA(3, tn, nxt);
    asm volatile("s_waitcnt lgkmcnt(4)" ::: "memory");
    __builtin_amdgcn_s_setprio(1);
    MMQ(0, 0, 4, 0);
    __builtin_amdgcn_s_setprio(0);
    asm volatile("s_waitcnt vmcnt(8)" ::: "memory");
    __builtin_amdgcn_s_barrier();
    // P2: M02 split, a1 reload interleaved into the dead af[] halves
    asm volatile("s_waitcnt lgkmcnt(0)" ::: "memory");
    __builtin_amdgcn_s_setprio(1);
    MMQ(0, 0, 2, 2);
    __builtin_amdgcn_s_setprio(0);
    LDA_II(1, 0); LDA_II(1, 1);
    __builtin_amdgcn_s_setprio(1);
    MMQ(0, 2, 4, 2);
    __builtin_amdgcn_s_setprio(0);
    LDA_II(1, 2); LDA_II(1, 3);
    __builtin_amdgcn_s_barrier();
    // P3: stage Bq0,Bq1(t+2)->cur (all B reads retired) | M12
    SB(0, tn2, cur); SB(1, tn2, cur);
    asm volatile("s_waitcnt lgkmcnt(0)" ::: "memory");
    __builtin_amdgcn_s_setprio(1);
    MMQ(1, 0, 4, 2);
    __builtin_amdgcn_s_setprio(0);
    __builtin_amdgcn_s_barrier();
    // P4: stage Aq0,Aq2(t+2)->cur | M10 (regs only) | vmcnt(6)
    SA(0, tn2, cur); SA(2, tn2, cur);
    __builtin_amdgcn_s_setprio(1);
    MMQ(1, 0, 4, 0);
    __builtin_amdgcn_s_setprio(0);
    asm volatile("s_waitcnt vmcnt(6)" ::: "memory");
    __builtin_amdgcn_s_barrier();
  }

  // epilogue: drain our async LDS writes before reuse/exit
  asm volatile("s_waitcnt vmcnt(0)" ::: "memory");
  const int wq = nb >> 2;                 // 0=q,1=k,2=v (block-uniform)
  const int h  = (nb & 3) * 4 + wn;       // head (wave-uniform)
  if (wq < 2) {
    ushort_t* base = ((wq == 0) ? q_bf : k_bf) + (size_t)(mb * 16 + h) * (SEQ * 64);
    const int tb = wm * 128 + quad * 4;
#pragma unroll
    for (int i = 0; i < 8; ++i)
#pragma unroll
      for (int j = 0; j < 4; ++j) {
        const int d = j * 16 + l15;
#pragma unroll
        for (int r = 0; r < 4; ++r)
          base[(size_t)(tb + i * 16 + r) * 64 + d] = f2bf(acc[i][j][r]);
      }
  } else {
    __builtin_amdgcn_s_barrier();  // all waves drained -> safe to overwrite smem
    ushort_t* L = &smem[wave * 4608];   // 64x72-pad transpose tile per wave
    ushort_t* vbase = vT_bf + (size_t)(mb * 16 + h) * (64 * SEQ) + wm * 128;
    const int tc = (lane & 7) * 8;
#pragma unroll
    for (int g = 0; g < 2; ++g) {
#pragma unroll
      for (int ii = 0; ii < 4; ++ii)
#pragma unroll
        for (int j = 0; j < 4; ++j) {
          f32x4 v = acc[g * 4 + ii][j];
          uint_t lo = (uint_t)f2bf(v[0]) | ((uint_t)f2bf(v[1]) << 16);
          uint_t hi = (uint_t)f2bf(v[2]) | ((uint_t)f2bf(v[3]) << 16);
          *(uint2*)&L[(j * 16 + l15) * 72 + ii * 16 + quad * 4] = make_uint2(lo, hi);
        }
#pragma unroll
      for (int u = 0; u < 8; ++u) {
        const int d = u * 8 + r8;
        uint4 val = *(const uint4*)&L[d * 72 + tc];
        *(uint4*)&vbase[(size_t)d * SEQ + g * 64 + tc] = val;
      }
    }
  }
#undef SA
#undef SB
#undef LDA_II
#undef LDB_J
#undef MMQ
}

// ---------------- stats: partial l[t,s], 16 bh per block via cross-wave LDS reduce ----
__global__ __launch_bounds__(256)
void stats_mfma(const ushort_t* __restrict__ qb, const ushort_t* __restrict__ kb,
                float* __restrict__ part_l) {
  const int p = blockIdx.x, g = blockIdx.y;   // g 0..63 -> one slot per block
  int tt, ss;
  if (p < 4) { tt = p; ss = p; }
  else {
    const int idx = p - 4;
    tt = (idx < 3) ? 0 : (idx < 5) ? 1 : 2;
    ss = (idx < 3) ? idx + 1 : (idx < 5) ? idx - 1 : 3;
  }
  const bool diag = (p < 4);
  const int tid = threadIdx.x, wave = tid >> 6, lane = tid & 63;
  const int l15 = lane & 15, quad = lane >> 4;

  __shared__ __attribute__((aligned(16))) float red[4][64 * 68];  // stride 68: 16B-aligned rows

  f32x4 lacc[4][4] = {};

  for (int i4 = 0; i4 < 4; ++i4) {
    const int bp = g * 16 + wave * 4 + i4;
    const int bh = (bp & 63) * 16 + (bp >> 6);
    const ushort_t* qt = qb + (size_t)bh * (SEQ * 64) + (size_t)(tt * 64) * 64;
    const ushort_t* kt = kb + (size_t)bh * (SEQ * 64) + (size_t)(ss * 64) * 64;
    bf16x8 aq[4][2], bk[4][2];
#pragma unroll
    for (int m = 0; m < 4; ++m)
#pragma unroll
      for (int ks = 0; ks < 2; ++ks) {
        aq[m][ks] = *(const bf16x8*)&qt[(m * 16 + l15) * 64 + ks * 32 + quad * 8];
        bk[m][ks] = *(const bf16x8*)&kt[(m * 16 + l15) * 64 + ks * 32 + quad * 8];
      }
    f32x4 sf[4][4] = {};
#pragma unroll
    for (int ks = 0; ks < 2; ++ks)
#pragma unroll
      for (int m = 0; m < 4; ++m)
#pragma unroll
        for (int n = 0; n < 4; ++n)
          sf[m][n] = __builtin_amdgcn_mfma_f32_16x16x32_bf16(aq[m][ks], bk[n][ks], sf[m][n], 0, 0, 0);
#pragma unroll
    for (int m = 0; m < 4; ++m)
#pragma unroll
      for (int n = 0; n < 4; ++n)
#pragma unroll
        for (int r = 0; r < 4; ++r) {
          float e = __expf(sf[m][n][r] * SCALE);
          if (diag) {
            const int t = tt * 64 + m * 16 + quad * 4 + r;
            const int s = ss * 64 + n * 16 + l15;
            e = (s > t) ? e : 1.0f;
          }
          lacc[m][n][r] += e;
        }
  }
  // per-wave tile -> LDS
  float* R = red[wave];
#pragma unroll
  for (int m = 0; m < 4; ++m)
#pragma unroll
    for (int r = 0; r < 4; ++r) {
      const int row = m * 16 + quad * 4 + r;
#pragma unroll
      for (int n = 0; n < 4; ++n)
        R[row * 68 + n * 16 + l15] = lacc[m][n][r];
    }
  __syncthreads();
  // cross-wave reduce: thread -> (row tid>>2, 16-col chunk), vectorized
  const int trow = tid >> 2, c0 = (tid & 3) * 16;
  const float* r0 = &red[0][trow * 68 + c0];
  const float* r1 = &red[1][trow * 68 + c0];
  const float* r2 = &red[2][trow * 68 + c0];
  const float* r3 = &red[3][trow * 68 + c0];
  float* pl = part_l + (size_t)g * (SEQ * SEQ) + (size_t)(tt * 64 + trow) * SEQ + ss * 64 + c0;
#pragma unroll
  for (int c = 0; c < 16; c += 4) {
    float4 s0 = *(const float4*)&r0[c];
    float4 s1 = *(const float4*)&r1[c];
    float4 s2 = *(const float4*)&r2[c];
    float4 s3 = *(const float4*)&r3[c];
    float4 o;
    o.x = (s0.x + s1.x) + (s2.x + s3.x);
    o.y = (s0.y + s1.y) + (s2.y + s3.y);
    o.z = (s0.z + s1.z) + (s2.z + s3.z);
    o.w = (s0.w + s1.w) + (s2.w + s3.w);
    *(float4*)&pl[c] = o;
  }
}

// ---------------- merge: sum 64 slots -> inv_lT[s][t]; 8 accumulators for MLP --------
__global__ __launch_bounds__(256)
void merge_kernel(const float* __restrict__ part_l, float* __restrict__ inv_lT) {
  const int i = blockIdx.x * 256 + threadIdx.x;  // t*256+s
  const int t = i >> 8, s = i & 255;
  float invv;
  if (s <= t) invv = 1.0f / 1024.0f;
  else {
    const float* p = part_l + i;
    float a0 = 0.f, a1 = 0.f, a2 = 0.f, a3 = 0.f,
          a4 = 0.f, a5 = 0.f, a6 = 0.f, a7 = 0.f;
    for (int g = 0; g < 64; g += 8) {
      const float* q = p + ((size_t)g << 16);
      a0 += q[0ull << 16]; a1 += q[1ull << 16]; a2 += q[2ull << 16]; a3 += q[3ull << 16];
      a4 += q[4ull << 16]; a5 += q[5ull << 16]; a6 += q[6ull << 16]; a7 += q[7ull << 16];
    }
    invv = 1.0f / (((a0 + a1) + (a2 + a3)) + ((a4 + a5) + (a6 + a7)));
  }
  inv_lT[s * SEQ + t] = invv;
}

// ---------------- pv: recompute S^T, P=e*inv (bf16, LDS), O = P.V via MFMA ----------------
__global__ __launch_bounds__(256)
void pv_mfma(const ushort_t* __restrict__ qb, const ushort_t* __restrict__ kb,
             const ushort_t* __restrict__ vtb, const float* __restrict__ inv_lT,
             float* __restrict__ out) {
  const int bh = blockIdx.x;
  const int b = bh >> 4, h = bh & 15;
  const int tid = threadIdx.x, wave = tid >> 6, lane = tid & 63;
  const int l15 = lane & 15, quad = lane >> 4;
  const int t0 = wave * 64;

  __shared__ ushort_t Plds[4][64][72];
  ushort_t (*Pw)[72] = Plds[wave];

  const ushort_t* qq = qb + (size_t)bh * (SEQ * 64);
  const ushort_t* kk = kb + (size_t)bh * (SEQ * 64);
  const ushort_t* vv = vtb + (size_t)bh * (64 * SEQ);

  bf16x8 qf[4][2];
#pragma unroll
  for (int nt = 0; nt < 4; ++nt)
#pragma unroll
    for (int ks = 0; ks < 2; ++ks)
      qf[nt][ks] = *(const bf16x8*)&qq[(t0 + nt * 16 + l15) * 64 + ks * 32 + quad * 8];

  f32x4 o[4][4] = {};

  for (int sc = 0; sc < 4; ++sc) {
    if (sc < wave) {
      const uint_t c = 0x3A803A80u;  // bf16 1/1024, exact
      const uint4 cc = make_uint4(c, c, c, c);
#pragma unroll
      for (int u = 0; u < 8; ++u) *(uint4*)&Pw[lane][u * 8] = cc;
    } else {
      bf16x8 kf[4][2];
#pragma unroll
      for (int ms = 0; ms < 4; ++ms)
#pragma unroll
        for (int ks = 0; ks < 2; ++ks)
          kf[ms][ks] = *(const bf16x8*)&kk[(sc * 64 + ms * 16 + l15) * 64 + ks * 32 + quad * 8];
      f32x4 sf[4][4] = {};
#pragma unroll
      for (int ks = 0; ks < 2; ++ks)
#pragma unroll
        for (int ms = 0; ms < 4; ++ms)
#pragma unroll
          for (int nt = 0; nt < 4; ++nt)
            sf[ms][nt] = __builtin_amdgcn_mfma_f32_16x16x32_bf16(kf[ms][ks], qf[nt][ks], sf[ms][nt], 0, 0, 0);
      const bool dg = (sc == wave);
      const int t = t0 + l15;
#pragma unroll
      for (int ms = 0; ms < 4; ++ms)
#pragma unroll
        for (int nt = 0; nt < 4; ++nt) {
          const int sb = sc * 64 + ms * 16 + quad * 4;
          const int tc = t + nt * 16;
          ushort_t pb[4];
#pragma unroll
          for (int r = 0; r < 4; ++r) {
            const int s = sb + r;
            float e = __expf(sf[ms][nt][r] * SCALE);
            if (dg) e = (s > tc) ? e : 1.0f;
            pb[r] = f2bf(e * inv_lT[(size_t)s * SEQ + tc]);
          }
          uint_t lo = (uint_t)pb[0] | ((uint_t)pb[1] << 16);
          uint_t hi = (uint_t)pb[2] | ((uint_t)pb[3] << 16);
          *(uint2*)&Pw[nt * 16 + l15][ms * 16 + quad * 4] = make_uint2(lo, hi);
        }
    }
    bf16x8 vf[4][2], pf[4][2];
#pragma unroll
    for (int nd = 0; nd < 4; ++nd)
#pragma unroll
      for (int ks = 0; ks < 2; ++ks)
        vf[nd][ks] = *(const bf16x8*)&vv[(nd * 16 + l15) * SEQ + sc * 64 + ks * 32 + quad * 8];
#pragma unroll
    for (int mt = 0; mt < 4; ++mt)
#pragma unroll
      for (int ks = 0; ks < 2; ++ks)
        pf[mt][ks] = *(const bf16x8*)&Pw[mt * 16 + l15][ks * 32 + quad * 8];
#pragma unroll
    for (int ks = 0; ks < 2; ++ks)
#pragma unroll
      for (int mt = 0; mt < 4; ++mt)
#pragma unroll
        for (int nd = 0; nd < 4; ++nd)
          o[mt][nd] = __builtin_amdgcn_mfma_f32_16x16x32_bf16(pf[mt][ks], vf[nd][ks], o[mt][nd], 0, 0, 0);
  }

  float* ob = out + (size_t)b * SEQ * DIM + h * 64;
#pragma unroll
  for (int mt = 0; mt < 4; ++mt)
#pragma unroll
    for (int r = 0; r < 4; ++r) {
      const int t = t0 + mt * 16 + quad * 4 + r;
#pragma unroll
      for (int nd = 0; nd < 4; ++nd)
        ob[(size_t)t * DIM + nd * 16 + l15] = o[mt][nd][r];
    }
}

extern "C" void kernel_launch(void* const* d_in, const int* in_sizes, int n_in,
                              void* d_out, int out_size, void* d_ws, size_t ws_size,
                              hipStream_t stream) {
  const float* x   = (const float*)d_in[0];
  const float* pos = (const float*)d_in[1];
  const float* Wq  = (const float*)d_in[2];
  const float* Wk  = (const float*)d_in[3];
  const float* Wv  = (const float*)d_in[4];
  float* out = (float*)d_out;

  // A_bf (33.5 MB) + Bp (6.3 MB) live in d_out (67 MB); both are dead before
  // pv_mfma fully overwrites d_out.
  ushort_t* Ab = (ushort_t*)d_out;
  ushort_t* Bp = (ushort_t*)((char*)d_out + 33554432);

  char* W = (char*)d_ws;
  ushort_t* q_bf   = (ushort_t*)(W);                  //  33,554,432 B  [b][h][t][d]
  ushort_t* k_bf   = (ushort_t*)(W + 33554432);       //  33,554,432 B
  ushort_t* vT_bf  = (ushort_t*)(W + 67108864);       //  33,554,432 B  [b][h][d][t]
  float*    part_l = (float*)  (W + 100663296);       //  16,777,216 B  (64 slots)
  float*    inv_lT = (float*)  (W + 167772160);       //     262,144 B

  prep_a<<<dim3(8192), 256, 0, stream>>>(x, pos, Ab);
  pack_w<<<dim3(4, 128, 3), 256, 0, stream>>>(Wq, Wk, Wv, Bp);
  qkv_mfma<<<dim3(12, 64), 512, 0, stream>>>(Ab, Bp, q_bf, k_bf, vT_bf);
  stats_mfma<<<dim3(10, 64), 256, 0, stream>>>(q_bf, k_bf, part_l);
  merge_kernel<<<dim3(SEQ * SEQ / 256), 256, 0, stream>>>(part_l, inv_lT);
  pv_mfma<<<dim3(1024), 256, 0, stream>>>(q_bf, k_bf, vT_bf, inv_lT, out);
}